// Round 4
// baseline (914.464 us; speedup 1.0000x reference)
//
#include <hip/hip_runtime.h>
#include <hip/hip_bf16.h>

// Int8Linear: out[B,T,OUT] = x[B,T,IN] @ (w_int8*scale)^T + bias
// M = B*T = 8192, N = OUT = 11008, K = IN = 4096
#define MDIM 8192
#define NDIM 11008
#define KDIM 4096

#define BM 256
#define BN 256
#define BK 64
#define NT (KDIM / BK)   // 64 K-tiles

typedef __attribute__((ext_vector_type(8))) short short8;
typedef __attribute__((ext_vector_type(4))) float f32x4;

// ---------------- conversion kernels (memory-bound) ----------------

__device__ __forceinline__ unsigned short f2bf_rne(float f) {
  unsigned int u = __float_as_uint(f);
  u += 0x7fffu + ((u >> 16) & 1u);   // round-to-nearest-even
  return (unsigned short)(u >> 16);
}

__global__ void cvt_x_kernel(const float4* __restrict__ x,
                             ushort4* __restrict__ y, int n4) {
  int stride = gridDim.x * blockDim.x;
  for (int i = blockIdx.x * blockDim.x + threadIdx.x; i < n4; i += stride) {
    float4 v = x[i];
    ushort4 o;
    o.x = f2bf_rne(v.x); o.y = f2bf_rne(v.y);
    o.z = f2bf_rne(v.z); o.w = f2bf_rne(v.w);
    y[i] = o;
  }
}

// int8 values in [-127,127] are EXACT in bf16
__global__ void cvt_w_kernel(const int4* __restrict__ w,
                             ushort4* __restrict__ y, int n4) {
  int stride = gridDim.x * blockDim.x;
  for (int i = blockIdx.x * blockDim.x + threadIdx.x; i < n4; i += stride) {
    int4 v = w[i];
    ushort4 o;
    o.x = f2bf_rne((float)v.x); o.y = f2bf_rne((float)v.y);
    o.z = f2bf_rne((float)v.z); o.w = f2bf_rne((float)v.w);
    y[i] = o;
  }
}

// ---------------- 256x256 2-phase/K-tile bf16 MFMA GEMM ----------------
// C[m,n] = scale[n] * sum_k A[m,k]*Bt[n,k] + bias[n]
// 512 threads = 8 waves (2 M x 4 N); per-wave output 128x64.
// LDS: per operand [2 buf][2 khalf][256][32] bf16 = 64 KB; total 128 KB.
// Phase = {12 ds_read_b128 + 4 global_load_lds, MFMA x32, vmcnt(8), barrier}.
// Counted lgkm waits are compiler-inserted (plain C++ LDS loads).
// Steady invariant entering PH0(T): outstanding vm = [T.kh1(4), (T+1).kh0(4)].
// R4: column-major block traversal within XCD chunk (B-panel L2-resident,
// A served from L3) + non-temporal C stores (write stream bypasses L2/L3).

#define SBARR() __builtin_amdgcn_sched_barrier(0)
#define BARR()  __builtin_amdgcn_s_barrier()
#define VMW_(n) asm volatile("s_waitcnt vmcnt(" #n ")" ::: "memory")
#define VMW(n)  VMW_(n)

#define GLL(SRC, DST) \
  __builtin_amdgcn_global_load_lds( \
      (const __attribute__((address_space(1))) void*)(SRC), \
      (__attribute__((address_space(3))) void*)(DST), 16, 0, 0)

// stage one (operand, khalf) unit of K-tile T: 2 loads/thread, linear LDS dest
#define STAGE(GSRC, LBASE, UOFF, T, KH) do { \
    const char* _s = (GSRC) + (T) * 128 + (KH) * 64; \
    GLL(_s, (LBASE) + (UOFF) + w * 1024); \
    GLL(_s + rstep, (LBASE) + (UOFF) + w * 1024 + 8192); \
  } while (0)

// swizzled fragment read (16B = 8 bf16 along K for one row)
#define RD(LBASE, UOFF, ROW) \
  (*(const short8*)((LBASE) + (UOFF) + (ROW) * 64 + kbs))

#define MFMA16(AF, MOFF) do { \
    _Pragma("unroll") for (int mi = 0; mi < 4; ++mi) \
    _Pragma("unroll") for (int ni = 0; ni < 4; ++ni) \
      acc[(MOFF) + mi][ni] = __builtin_amdgcn_mfma_f32_16x16x32_bf16( \
          AF[mi], bf[ni], acc[(MOFF) + mi][ni], 0, 0, 0); \
  } while (0)

// One phase. U = LDS unit byte offset for reads. SD = do stage, SU = stage LDS
// unit offset, ST/SK = staged tile/khalf. VN = vmcnt count. TAILP = skip wait+barrier.
#define PHASE(U, SD, SU, ST, SK, VN, TAILP) do { \
    _Pragma("unroll") for (int ni = 0; ni < 4; ++ni) bf[ni]  = RD(ldsB, U, brow0 + ni * 16); \
    _Pragma("unroll") for (int mi = 0; mi < 4; ++mi) af[mi]  = RD(ldsA, U, arow0 + mi * 16); \
    _Pragma("unroll") for (int mi = 0; mi < 4; ++mi) af2[mi] = RD(ldsA, U, arow0 + 64 + mi * 16); \
    if (SD) { STAGE(gAs, ldsA, SU, ST, SK); STAGE(gBs, ldsB, SU, ST, SK); } \
    SBARR(); \
    __builtin_amdgcn_s_setprio(1); \
    MFMA16(af, 0); \
    MFMA16(af2, 4); \
    __builtin_amdgcn_s_setprio(0); \
    SBARR(); \
    if (!(TAILP)) { VMW(VN); BARR(); SBARR(); } \
  } while (0)

// K-tile = 2 phases. PH0 reads kh0, stages (T+1).kh1 into buf^1.
// PH1 reads kh1, stages (T+2).kh0 into buf.
#define KTILE(T, B_, S1, S0, N0, N1, LAST) do { \
    PHASE((B_) * 32768,         S1, ((B_) ^ 1) * 32768 + 16384, (T) + 1, 1, N0, 0); \
    PHASE((B_) * 32768 + 16384, S0, (B_) * 32768,               (T) + 2, 0, N1, LAST); \
  } while (0)

__global__ __launch_bounds__(512, 2) void gemm_bf16_kernel(
    const unsigned short* __restrict__ A,
    const unsigned short* __restrict__ Bt,
    const float* __restrict__ scale,
    const float* __restrict__ bias,
    float* __restrict__ C)
{
  __shared__ __attribute__((aligned(16))) unsigned short As[2][2][256][32];
  __shared__ __attribute__((aligned(16))) unsigned short Bs[2][2][256][32];

  const int nbr = MDIM / BM;  // 32 row-blocks; grid = 32*43 = 1376 = 8*172
  int bid = blockIdx.x;
  int cpx = gridDim.x >> 3;
  int swz = (bid & 7) * cpx + (bid >> 3);   // bijective XCD swizzle
  // column-major within chunk: consecutive swz -> same bcol, brow fastest.
  // B-panel (2 MB) stays L2-resident across its 32 consecutive uses;
  // A panels re-served from L3 (67 MB total < 256 MB).
  int brow = (swz % nbr) * BM;
  int bcol = (swz / nbr) * BN;

  int tid  = threadIdx.x;
  int lane = tid & 63;
  int w    = tid >> 6;
  int wr   = (w >> 2) & 1;   // M-wave (2)
  int wc   = w & 3;          // N-wave (4)

  int ra = lane & 15;                         // fragment row within 16
  int kb = (lane >> 4) * 16;                  // byte offset along K (64B row)
  int kbs = kb ^ (((ra >> 1) & 3) << 4);      // T2 swizzled read offset

  int arow0 = wr * 128 + ra;                  // wave's A base row + frag row
  int brow0 = wc * 64 + ra;                   // wave's B base row + frag row

  // staging: thread covers granule g = w*64+lane (rows 0-127) and g+512;
  // inverse-swizzled source column (lane-constant)
  int srow = w * 16 + (lane >> 2);
  int csrc = (lane & 3) ^ ((lane >> 3) & 3);
  const char* gAs = (const char*)A  + (size_t)(brow + srow) * (KDIM * 2) + csrc * 16;
  const char* gBs = (const char*)Bt + (size_t)(bcol + srow) * (KDIM * 2) + csrc * 16;
  const size_t rstep = (size_t)128 * KDIM * 2;

  char* ldsA = (char*)&As[0][0][0][0];
  char* ldsB = (char*)&Bs[0][0][0][0];

  f32x4 acc[8][4] = {};
  short8 af[4], af2[4], bf[4];

  // prologue: t0.kh0, t0.kh1, t1.kh0 staged (12 loads); drain t0.kh0
  STAGE(gAs, ldsA, 0,     0, 0);  STAGE(gBs, ldsB, 0,     0, 0);
  STAGE(gAs, ldsA, 16384, 0, 1);  STAGE(gBs, ldsB, 16384, 0, 1);
  STAGE(gAs, ldsA, 32768, 1, 0);  STAGE(gBs, ldsB, 32768, 1, 0);
  VMW(8); BARR(); SBARR();

  // steady: T = 0..61
  for (int it = 0; it < NT / 2 - 1; ++it) {
    int t = it * 2;
    KTILE(t,     0, 1, 1, 8, 8, 0);
    KTILE(t + 1, 1, 1, 1, 8, 8, 0);
  }
  // tail: T = 62 (stage 63.kh1 only), T = 63 (no stage)
  KTILE(62, 0, 1, 0, 8, 4, 0);
  KTILE(63, 1, 0, 0, 0, 0, 1);

  // epilogue: C/D layout col = lane&15, row = (lane>>4)*4 + reg
  // non-temporal stores: don't evict A/B panels from L2/L3
  int col0 = bcol + wc * 64 + ra;
  int row0 = brow + wr * 128 + (lane >> 4) * 4;
#pragma unroll
  for (int n = 0; n < 4; ++n) {
    int ng = col0 + n * 16;
    float sc = scale[ng];
    float bi = bias[ng];
#pragma unroll
    for (int m = 0; m < 8; ++m) {
      int rg = row0 + m * 16;
#pragma unroll
      for (int j = 0; j < 4; ++j)
        __builtin_nontemporal_store(acc[m][n][j] * sc + bi,
                                    &C[(size_t)(rg + j) * NDIM + ng]);
    }
  }
}

// ---------------- fallback (only if d_ws is too small) ----------------

__global__ void naive_kernel(const float* __restrict__ x, const int* __restrict__ w,
                             const float* __restrict__ scale, const float* __restrict__ bias,
                             float* __restrict__ out)
{
  int n = blockIdx.x * blockDim.x + threadIdx.x;
  int m = blockIdx.y;
  if (n >= NDIM) return;
  const float* xr = x + (size_t)m * KDIM;
  const int* wrow = w + (size_t)n * KDIM;
  float s = 0.f;
  for (int k = 0; k < KDIM; ++k) s += xr[k] * (float)wrow[k];
  out[(size_t)m * NDIM + n] = s * scale[n] + bias[n];
}

// ---------------- launcher ----------------

extern "C" void kernel_launch(void* const* d_in, const int* in_sizes, int n_in,
                              void* d_out, int out_size, void* d_ws, size_t ws_size,
                              hipStream_t stream) {
  const float* x      = (const float*)d_in[0];
  const int*   w8     = (const int*)d_in[1];
  const float* wscale = (const float*)d_in[2];
  const float* bias   = (const float*)d_in[3];
  float* out = (float*)d_out;

  size_t abytes = (size_t)MDIM * KDIM * 2;  // 67.1 MB
  size_t bbytes = (size_t)NDIM * KDIM * 2;  // 90.2 MB

  if (ws_size >= abytes + bbytes) {
    unsigned short* Abf = (unsigned short*)d_ws;
    unsigned short* Bbf = (unsigned short*)((char*)d_ws + abytes);
    int n4x = (MDIM * KDIM) / 4;
    int n4w = (NDIM * KDIM) / 4;
    cvt_x_kernel<<<2048, 256, 0, stream>>>((const float4*)x, (ushort4*)Abf, n4x);
    cvt_w_kernel<<<2048, 256, 0, stream>>>((const int4*)w8, (ushort4*)Bbf, n4w);
    gemm_bf16_kernel<<<(MDIM / BM) * (NDIM / BN), 512, 0, stream>>>(Abf, Bbf, wscale, bias, out);
  } else {
    naive_kernel<<<dim3((NDIM + 255) / 256, MDIM), 256, 0, stream>>>(x, w8, wscale, bias, out);
  }
}

// Round 5
// 506.124 us; speedup vs baseline: 1.8068x; 1.8068x over previous
//
#include <hip/hip_runtime.h>
#include <hip/hip_bf16.h>

// Int8Linear: out[B,T,OUT] = x[B,T,IN] @ (w_int8*scale)^T + bias
// M = B*T = 8192, N = OUT = 11008, K = IN = 4096
// Full-int8 path: x per-token absmax-quantized to i8, W exact i8,
// mfma_i32_16x16x64_i8 (2x bf16 rate), exact i32 accumulation,
// epilogue out = acc * xs[m] * wscale[n] + bias[n].
#define MDIM 8192
#define NDIM 11008
#define KDIM 4096

#define BM 256
#define BN 256
#define BK 64
#define NT (KDIM / BK)   // 64 K-tiles

typedef __attribute__((ext_vector_type(4))) int   int4v;
typedef __attribute__((ext_vector_type(4))) float f32x4;

// ---------------- x quantization: per-token absmax -> i8 ----------------

__global__ __launch_bounds__(256) void quant_x_kernel(const float* __restrict__ x,
                                                      int* __restrict__ q,
                                                      float* __restrict__ xs) {
  int row = blockIdx.x;
  int tid = threadIdx.x;
  const float4* xr = (const float4*)(x + (size_t)row * KDIM);
  float4 v[4];
  float amax = 0.f;
#pragma unroll
  for (int i = 0; i < 4; ++i) {
    v[i] = xr[tid + i * 256];
    amax = fmaxf(amax, fmaxf(fmaxf(fabsf(v[i].x), fabsf(v[i].y)),
                             fmaxf(fabsf(v[i].z), fabsf(v[i].w))));
  }
#pragma unroll
  for (int off = 32; off; off >>= 1)
    amax = fmaxf(amax, __shfl_xor(amax, off));
  __shared__ float smax[4];
  if ((tid & 63) == 0) smax[tid >> 6] = amax;
  __syncthreads();
  amax = fmaxf(fmaxf(smax[0], smax[1]), fmaxf(smax[2], smax[3]));
  amax = fmaxf(amax, 1e-20f);
  float inv = 127.f / amax;
  if (tid == 0) xs[row] = amax * (1.f / 127.f);
  int* qr = q + (size_t)row * (KDIM / 4);
#pragma unroll
  for (int i = 0; i < 4; ++i) {
    int a = (int)rintf(v[i].x * inv) & 255;
    int b = (int)rintf(v[i].y * inv) & 255;
    int c = (int)rintf(v[i].z * inv) & 255;
    int d = (int)rintf(v[i].w * inv);
    qr[tid + i * 256] = a | (b << 8) | (c << 16) | (d << 24);
  }
}

// ---------------- W pack: int32 -> i8 (exact) ----------------

__global__ void cvt_w_kernel(const int* __restrict__ w, int* __restrict__ q, int n) {
  int stride = gridDim.x * blockDim.x;
  for (int i = blockIdx.x * blockDim.x + threadIdx.x; i < n; i += stride) {
    int4v v = *(const int4v*)(w + (size_t)i * 4);
    q[i] = (v.x & 255) | ((v.y & 255) << 8) | ((v.z & 255) << 16) | (v.w << 24);
  }
}

// ---------------- 256x256 int8 MFMA GEMM ----------------
// A: [M,K] i8 row-major, Bt: [N,K] i8 row-major.
// 512 threads = 8 waves (2 M x 4 N); per-wave output 128x64.
// LDS: per operand [4-ring][256 rows][64 B] = 64 KB; total 128 KB.
// Tile = {12 ds_read_b128, 2 MFMA half-clusters (16 each), stage A+B of T+2,
//         vmcnt(4), 1 barrier}. Landing deadline ~2 tiles > HBM latency.
// Byte-level LDS geometry (64B rows, 16B granules, XOR swizzle, GLL mapping)
// identical to the verified R3 bf16 kernel.

#define SBARR() __builtin_amdgcn_sched_barrier(0)
#define BARR()  __builtin_amdgcn_s_barrier()
#define VMW_(n) asm volatile("s_waitcnt vmcnt(" #n ")" ::: "memory")
#define VMW(n)  VMW_(n)

#define GLL(SRC, DST) \
  __builtin_amdgcn_global_load_lds( \
      (const __attribute__((address_space(1))) void*)(SRC), \
      (__attribute__((address_space(3))) void*)(DST), 16, 0, 0)

// stage one operand's K-tile T (16KB): 2 loads/thread, linear LDS dest
#define STAGE(GSRC, LBASE, BUFI, T) do { \
    const char* _s = (GSRC) + (T) * 64; \
    GLL(_s, (LBASE) + (BUFI) * 16384 + w * 1024); \
    GLL(_s + rstep, (LBASE) + (BUFI) * 16384 + w * 1024 + 8192); \
  } while (0)

// swizzled fragment read (16B = 16 i8 along K for one row)
#define RD(LB, BUFI, ROW) \
  (*(const int4v*)((LB) + (BUFI) * 16384 + (ROW) * 64 + kbs))

#define MFMA16(AF, MOFF) do { \
    _Pragma("unroll") for (int mi = 0; mi < 4; ++mi) \
    _Pragma("unroll") for (int ni = 0; ni < 4; ++ni) \
      acc[(MOFF) + mi][ni] = __builtin_amdgcn_mfma_i32_16x16x64_i8( \
          af[mi], bf[ni], acc[(MOFF) + mi][ni], 0, 0, 0); \
  } while (0)

// One K-tile. B_ = ring slot (compile-time), SD = stage T+2, VN = vmcnt arg,
// TAIL = last tile (skip wait+barrier).
#define KT(T, B_, SD, VN, TAIL) do { \
    _Pragma("unroll") for (int ni = 0; ni < 4; ++ni) bf[ni] = RD(ldsB, B_, brow0 + ni * 16); \
    _Pragma("unroll") for (int mi = 0; mi < 4; ++mi) af[mi] = RD(ldsA, B_, arow0 + mi * 16); \
    if (SD) STAGE(gAs, ldsA, ((B_) + 2) & 3, (T) + 2); \
    SBARR(); \
    __builtin_amdgcn_s_setprio(1); MFMA16(af, 0); __builtin_amdgcn_s_setprio(0); \
    SBARR(); \
    _Pragma("unroll") for (int mi = 0; mi < 4; ++mi) af[mi] = RD(ldsA, B_, arow0 + 64 + mi * 16); \
    if (SD) STAGE(gBs, ldsB, ((B_) + 2) & 3, (T) + 2); \
    SBARR(); \
    __builtin_amdgcn_s_setprio(1); MFMA16(af, 4); __builtin_amdgcn_s_setprio(0); \
    SBARR(); \
    if (!(TAIL)) { VMW(VN); BARR(); SBARR(); } \
  } while (0)

__global__ __launch_bounds__(512, 2) void gemm_i8_kernel(
    const char* __restrict__ A,
    const char* __restrict__ Bt,
    const float* __restrict__ xs,
    const float* __restrict__ scale,
    const float* __restrict__ bias,
    float* __restrict__ C)
{
  __shared__ __attribute__((aligned(16))) char As[4][256][64];  // 64 KB
  __shared__ __attribute__((aligned(16))) char Bs[4][256][64];  // 64 KB

  const int nbc = NDIM / BN;  // 43 ; grid = 32*43 = 1376 = 8*172
  int bid = blockIdx.x;
  int cpx = gridDim.x >> 3;
  int swz = (bid & 7) * cpx + (bid >> 3);   // bijective XCD swizzle
  int brow = (swz / nbc) * BM;              // row-major within chunk (R3 config)
  int bcol = (swz % nbc) * BN;

  int tid  = threadIdx.x;
  int lane = tid & 63;
  int w    = tid >> 6;
  int wr   = (w >> 2) & 1;   // M-wave (2)
  int wc   = w & 3;          // N-wave (4)

  int ra = lane & 15;                         // fragment row within 16
  int kb = (lane >> 4) * 16;                  // byte offset along K (64B row)
  int kbs = kb ^ (((ra >> 1) & 3) << 4);      // T2 swizzled read offset

  int arow0 = wr * 128 + ra;                  // wave's A base row + frag row
  int brow0 = wc * 64 + ra;                   // wave's B base row + frag row

  // staging: thread covers granule g = w*64+lane (rows 0-127) and g+512;
  // inverse-swizzled source column (lane-constant)
  int srow = w * 16 + (lane >> 2);
  int csrc = (lane & 3) ^ ((lane >> 3) & 3);
  const char* gAs = A  + (size_t)(brow + srow) * KDIM + csrc * 16;
  const char* gBs = Bt + (size_t)(bcol + srow) * KDIM + csrc * 16;
  const size_t rstep = (size_t)128 * KDIM;

  char* ldsA = &As[0][0][0];
  char* ldsB = &Bs[0][0][0];

  int4v acc[8][4] = {};
  int4v af[4], bf[4];

  // prologue: tiles 0,1 staged into ring slots 0,1; drain tile 0
  STAGE(gAs, ldsA, 0, 0);  STAGE(gBs, ldsB, 0, 0);
  STAGE(gAs, ldsA, 1, 1);  STAGE(gBs, ldsB, 1, 1);
  VMW(4); BARR(); SBARR();

  // steady: tiles 0..61 stage T+2; invariant entering tile T: 4 loads
  // outstanding = (T+1).A + (T+1).B
  for (int t = 0; t < 56; t += 4) {
    KT(t,     0, 1, 4, 0);
    KT(t + 1, 1, 1, 4, 0);
    KT(t + 2, 2, 1, 4, 0);
    KT(t + 3, 3, 1, 4, 0);
  }
  KT(56, 0, 1, 4, 0);
  KT(57, 1, 1, 4, 0);
  KT(58, 2, 1, 4, 0);
  KT(59, 3, 1, 4, 0);
  KT(60, 0, 1, 4, 0);
  KT(61, 1, 1, 4, 0);
  KT(62, 2, 0, 0, 0);   // no stage; drain tile 63
  KT(63, 3, 0, 0, 1);   // last tile

  // epilogue: C/D layout col = lane&15, row = (lane>>4)*4 + reg (dtype-indep)
  int col0 = bcol + wc * 64 + ra;
  int row0 = brow + wr * 128 + (lane >> 4) * 4;
  float xr_[8][4];
#pragma unroll
  for (int m = 0; m < 8; ++m)
#pragma unroll
    for (int j = 0; j < 4; ++j)
      xr_[m][j] = xs[row0 - brow + brow + m * 16 + j];  // xs[row0 + m*16 + j]
#pragma unroll
  for (int n = 0; n < 4; ++n) {
    int ng = col0 + n * 16;
    float sc = scale[ng];
    float bi = bias[ng];
#pragma unroll
    for (int m = 0; m < 8; ++m) {
      int rg = row0 + m * 16;
#pragma unroll
      for (int j = 0; j < 4; ++j)
        C[(size_t)(rg + j) * NDIM + ng] = (float)acc[m][n][j] * (xr_[m][j] * sc) + bi;
    }
  }
}

// ---------------- fallback (only if d_ws is too small) ----------------

__global__ void naive_kernel(const float* __restrict__ x, const int* __restrict__ w,
                             const float* __restrict__ scale, const float* __restrict__ bias,
                             float* __restrict__ out)
{
  int n = blockIdx.x * blockDim.x + threadIdx.x;
  int m = blockIdx.y;
  if (n >= NDIM) return;
  const float* xr = x + (size_t)m * KDIM;
  const int* wrow = w + (size_t)n * KDIM;
  float s = 0.f;
  for (int k = 0; k < KDIM; ++k) s += xr[k] * (float)wrow[k];
  out[(size_t)m * NDIM + n] = s * scale[n] + bias[n];
}

// ---------------- launcher ----------------

extern "C" void kernel_launch(void* const* d_in, const int* in_sizes, int n_in,
                              void* d_out, int out_size, void* d_ws, size_t ws_size,
                              hipStream_t stream) {
  const float* x      = (const float*)d_in[0];
  const int*   w8     = (const int*)d_in[1];
  const float* wscale = (const float*)d_in[2];
  const float* bias   = (const float*)d_in[3];
  float* out = (float*)d_out;

  size_t aq = (size_t)MDIM * KDIM;   // 33.5 MB i8
  size_t bq = (size_t)NDIM * KDIM;   // 45.1 MB i8
  size_t xb = (size_t)MDIM * 4;      // 32 KB scales

  if (ws_size >= aq + bq + xb) {
    char* Aq = (char*)d_ws;
    char* Bq = (char*)d_ws + aq;
    float* xsp = (float*)((char*)d_ws + aq + bq);
    quant_x_kernel<<<MDIM, 256, 0, stream>>>(x, (int*)Aq, xsp);
    cvt_w_kernel<<<2048, 256, 0, stream>>>(w8, (int*)Bq, NDIM * KDIM / 4);
    gemm_i8_kernel<<<(MDIM / BM) * (NDIM / BN), 512, 0, stream>>>(
        Aq, Bq, xsp, wscale, bias, out);
  } else {
    naive_kernel<<<dim3((NDIM + 255) / 256, MDIM), 256, 0, stream>>>(x, w8, wscale, bias, out);
  }
}

// Round 6
// 466.584 us; speedup vs baseline: 1.9599x; 1.0847x over previous
//
#include <hip/hip_runtime.h>
#include <hip/hip_bf16.h>

// Int8Linear: out[B,T,OUT] = x[B,T,IN] @ (w_int8*scale)^T + bias
// M = B*T = 8192, N = OUT = 11008, K = IN = 4096
// Full-int8 path: x per-token absmax-quantized to i8, W exact i8,
// mfma_i32_16x16x64_i8 (2x bf16 rate), exact i32 accumulation,
// epilogue out = acc * xs[m] * wscale[n] + bias[n].
// R6: ONLY change vs R5 = non-temporal C stores (write stream must not
// evict the A/B panel working set from L2/L3; FETCH was 10x compulsory).
#define MDIM 8192
#define NDIM 11008
#define KDIM 4096

#define BM 256
#define BN 256
#define BK 64
#define NT (KDIM / BK)   // 64 K-tiles

typedef __attribute__((ext_vector_type(4))) int   int4v;
typedef __attribute__((ext_vector_type(4))) float f32x4;

// ---------------- x quantization: per-token absmax -> i8 ----------------

__global__ __launch_bounds__(256) void quant_x_kernel(const float* __restrict__ x,
                                                      int* __restrict__ q,
                                                      float* __restrict__ xs) {
  int row = blockIdx.x;
  int tid = threadIdx.x;
  const float4* xr = (const float4*)(x + (size_t)row * KDIM);
  float4 v[4];
  float amax = 0.f;
#pragma unroll
  for (int i = 0; i < 4; ++i) {
    v[i] = xr[tid + i * 256];
    amax = fmaxf(amax, fmaxf(fmaxf(fabsf(v[i].x), fabsf(v[i].y)),
                             fmaxf(fabsf(v[i].z), fabsf(v[i].w))));
  }
#pragma unroll
  for (int off = 32; off; off >>= 1)
    amax = fmaxf(amax, __shfl_xor(amax, off));
  __shared__ float smax[4];
  if ((tid & 63) == 0) smax[tid >> 6] = amax;
  __syncthreads();
  amax = fmaxf(fmaxf(smax[0], smax[1]), fmaxf(smax[2], smax[3]));
  amax = fmaxf(amax, 1e-20f);
  float inv = 127.f / amax;
  if (tid == 0) xs[row] = amax * (1.f / 127.f);
  int* qr = q + (size_t)row * (KDIM / 4);
#pragma unroll
  for (int i = 0; i < 4; ++i) {
    int a = (int)rintf(v[i].x * inv) & 255;
    int b = (int)rintf(v[i].y * inv) & 255;
    int c = (int)rintf(v[i].z * inv) & 255;
    int d = (int)rintf(v[i].w * inv);
    qr[tid + i * 256] = a | (b << 8) | (c << 16) | (d << 24);
  }
}

// ---------------- W pack: int32 -> i8 (exact) ----------------

__global__ void cvt_w_kernel(const int* __restrict__ w, int* __restrict__ q, int n) {
  int stride = gridDim.x * blockDim.x;
  for (int i = blockIdx.x * blockDim.x + threadIdx.x; i < n; i += stride) {
    int4v v = *(const int4v*)(w + (size_t)i * 4);
    q[i] = (v.x & 255) | ((v.y & 255) << 8) | ((v.z & 255) << 16) | (v.w << 24);
  }
}

// ---------------- 256x256 int8 MFMA GEMM ----------------
// A: [M,K] i8 row-major, Bt: [N,K] i8 row-major.
// 512 threads = 8 waves (2 M x 4 N); per-wave output 128x64.
// LDS: per operand [4-ring][256 rows][64 B] = 64 KB; total 128 KB.
// Tile = {12 ds_read_b128, 2 MFMA half-clusters (16 each), stage A+B of T+2,
//         vmcnt(4), 1 barrier}. Landing deadline ~2 tiles > HBM latency.

#define SBARR() __builtin_amdgcn_sched_barrier(0)
#define BARR()  __builtin_amdgcn_s_barrier()
#define VMW_(n) asm volatile("s_waitcnt vmcnt(" #n ")" ::: "memory")
#define VMW(n)  VMW_(n)

#define GLL(SRC, DST) \
  __builtin_amdgcn_global_load_lds( \
      (const __attribute__((address_space(1))) void*)(SRC), \
      (__attribute__((address_space(3))) void*)(DST), 16, 0, 0)

// stage one operand's K-tile T (16KB): 2 loads/thread, linear LDS dest
#define STAGE(GSRC, LBASE, BUFI, T) do { \
    const char* _s = (GSRC) + (T) * 64; \
    GLL(_s, (LBASE) + (BUFI) * 16384 + w * 1024); \
    GLL(_s + rstep, (LBASE) + (BUFI) * 16384 + w * 1024 + 8192); \
  } while (0)

// swizzled fragment read (16B = 16 i8 along K for one row)
#define RD(LB, BUFI, ROW) \
  (*(const int4v*)((LB) + (BUFI) * 16384 + (ROW) * 64 + kbs))

#define MFMA16(AF, MOFF) do { \
    _Pragma("unroll") for (int mi = 0; mi < 4; ++mi) \
    _Pragma("unroll") for (int ni = 0; ni < 4; ++ni) \
      acc[(MOFF) + mi][ni] = __builtin_amdgcn_mfma_i32_16x16x64_i8( \
          af[mi], bf[ni], acc[(MOFF) + mi][ni], 0, 0, 0); \
  } while (0)

// One K-tile. B_ = ring slot (compile-time), SD = stage T+2, VN = vmcnt arg,
// TAIL = last tile (skip wait+barrier).
#define KT(T, B_, SD, VN, TAIL) do { \
    _Pragma("unroll") for (int ni = 0; ni < 4; ++ni) bf[ni] = RD(ldsB, B_, brow0 + ni * 16); \
    _Pragma("unroll") for (int mi = 0; mi < 4; ++mi) af[mi] = RD(ldsA, B_, arow0 + mi * 16); \
    if (SD) STAGE(gAs, ldsA, ((B_) + 2) & 3, (T) + 2); \
    SBARR(); \
    __builtin_amdgcn_s_setprio(1); MFMA16(af, 0); __builtin_amdgcn_s_setprio(0); \
    SBARR(); \
    _Pragma("unroll") for (int mi = 0; mi < 4; ++mi) af[mi] = RD(ldsA, B_, arow0 + 64 + mi * 16); \
    if (SD) STAGE(gBs, ldsB, ((B_) + 2) & 3, (T) + 2); \
    SBARR(); \
    __builtin_amdgcn_s_setprio(1); MFMA16(af, 4); __builtin_amdgcn_s_setprio(0); \
    SBARR(); \
    if (!(TAIL)) { VMW(VN); BARR(); SBARR(); } \
  } while (0)

__global__ __launch_bounds__(512, 2) void gemm_i8_kernel(
    const char* __restrict__ A,
    const char* __restrict__ Bt,
    const float* __restrict__ xs,
    const float* __restrict__ scale,
    const float* __restrict__ bias,
    float* __restrict__ C)
{
  __shared__ __attribute__((aligned(16))) char As[4][256][64];  // 64 KB
  __shared__ __attribute__((aligned(16))) char Bs[4][256][64];  // 64 KB

  const int nbc = NDIM / BN;  // 43 ; grid = 32*43 = 1376 = 8*172
  int bid = blockIdx.x;
  int cpx = gridDim.x >> 3;
  int swz = (bid & 7) * cpx + (bid >> 3);   // bijective XCD swizzle
  int brow = (swz / nbc) * BM;              // row-major within chunk
  int bcol = (swz % nbc) * BN;

  int tid  = threadIdx.x;
  int lane = tid & 63;
  int w    = tid >> 6;
  int wr   = (w >> 2) & 1;   // M-wave (2)
  int wc   = w & 3;          // N-wave (4)

  int ra = lane & 15;                         // fragment row within 16
  int kb = (lane >> 4) * 16;                  // byte offset along K (64B row)
  int kbs = kb ^ (((ra >> 1) & 3) << 4);      // T2 swizzled read offset

  int arow0 = wr * 128 + ra;                  // wave's A base row + frag row
  int brow0 = wc * 64 + ra;                   // wave's B base row + frag row

  // staging: thread covers granule g = w*64+lane (rows 0-127) and g+512;
  // inverse-swizzled source column (lane-constant)
  int srow = w * 16 + (lane >> 2);
  int csrc = (lane & 3) ^ ((lane >> 3) & 3);
  const char* gAs = A  + (size_t)(brow + srow) * KDIM + csrc * 16;
  const char* gBs = Bt + (size_t)(bcol + srow) * KDIM + csrc * 16;
  const size_t rstep = (size_t)128 * KDIM;

  char* ldsA = &As[0][0][0];
  char* ldsB = &Bs[0][0][0];

  int4v acc[8][4] = {};
  int4v af[4], bf[4];

  // prologue: tiles 0,1 staged into ring slots 0,1; drain tile 0
  STAGE(gAs, ldsA, 0, 0);  STAGE(gBs, ldsB, 0, 0);
  STAGE(gAs, ldsA, 1, 1);  STAGE(gBs, ldsB, 1, 1);
  VMW(4); BARR(); SBARR();

  // steady: tiles 0..61 stage T+2; invariant entering tile T: 4 loads
  // outstanding = (T+1).A + (T+1).B
  for (int t = 0; t < 56; t += 4) {
    KT(t,     0, 1, 4, 0);
    KT(t + 1, 1, 1, 4, 0);
    KT(t + 2, 2, 1, 4, 0);
    KT(t + 3, 3, 1, 4, 0);
  }
  KT(56, 0, 1, 4, 0);
  KT(57, 1, 1, 4, 0);
  KT(58, 2, 1, 4, 0);
  KT(59, 3, 1, 4, 0);
  KT(60, 0, 1, 4, 0);
  KT(61, 1, 1, 4, 0);
  KT(62, 2, 0, 0, 0);   // no stage; drain tile 63
  KT(63, 3, 0, 0, 1);   // last tile

  // epilogue: C/D layout col = lane&15, row = (lane>>4)*4 + reg (dtype-indep)
  // NON-TEMPORAL stores: the 360 MB write stream must not evict A/B panels.
  int col0 = bcol + wc * 64 + ra;
  int row0 = brow + wr * 128 + (lane >> 4) * 4;
  float xr_[8][4];
#pragma unroll
  for (int m = 0; m < 8; ++m)
#pragma unroll
    for (int j = 0; j < 4; ++j)
      xr_[m][j] = xs[row0 + m * 16 + j];
#pragma unroll
  for (int n = 0; n < 4; ++n) {
    int ng = col0 + n * 16;
    float sc = scale[ng];
    float bi = bias[ng];
#pragma unroll
    for (int m = 0; m < 8; ++m) {
      int rg = row0 + m * 16;
#pragma unroll
      for (int j = 0; j < 4; ++j)
        __builtin_nontemporal_store((float)acc[m][n][j] * (xr_[m][j] * sc) + bi,
                                    &C[(size_t)(rg + j) * NDIM + ng]);
    }
  }
}

// ---------------- fallback (only if d_ws is too small) ----------------

__global__ void naive_kernel(const float* __restrict__ x, const int* __restrict__ w,
                             const float* __restrict__ scale, const float* __restrict__ bias,
                             float* __restrict__ out)
{
  int n = blockIdx.x * blockDim.x + threadIdx.x;
  int m = blockIdx.y;
  if (n >= NDIM) return;
  const float* xr = x + (size_t)m * KDIM;
  const int* wrow = w + (size_t)n * KDIM;
  float s = 0.f;
  for (int k = 0; k < KDIM; ++k) s += xr[k] * (float)wrow[k];
  out[(size_t)m * NDIM + n] = s * scale[n] + bias[n];
}

// ---------------- launcher ----------------

extern "C" void kernel_launch(void* const* d_in, const int* in_sizes, int n_in,
                              void* d_out, int out_size, void* d_ws, size_t ws_size,
                              hipStream_t stream) {
  const float* x      = (const float*)d_in[0];
  const int*   w8     = (const int*)d_in[1];
  const float* wscale = (const float*)d_in[2];
  const float* bias   = (const float*)d_in[3];
  float* out = (float*)d_out;

  size_t aq = (size_t)MDIM * KDIM;   // 33.5 MB i8
  size_t bq = (size_t)NDIM * KDIM;   // 45.1 MB i8
  size_t xb = (size_t)MDIM * 4;      // 32 KB scales

  if (ws_size >= aq + bq + xb) {
    char* Aq = (char*)d_ws;
    char* Bq = (char*)d_ws + aq;
    float* xsp = (float*)((char*)d_ws + aq + bq);
    quant_x_kernel<<<MDIM, 256, 0, stream>>>(x, (int*)Aq, xsp);
    cvt_w_kernel<<<2048, 256, 0, stream>>>(w8, (int*)Bq, NDIM * KDIM / 4);
    gemm_i8_kernel<<<(MDIM / BM) * (NDIM / BN), 512, 0, stream>>>(
        Aq, Bq, xsp, wscale, bias, out);
  } else {
    naive_kernel<<<dim3((NDIM + 255) / 256, MDIM), 256, 0, stream>>>(x, w8, wscale, bias, out);
  }
}